// Round 14
// baseline (22.024 us; speedup 1.0000x reference)
//
#include <hip/hip_runtime.h>

#define BLOCK 256
#define SEGS  224           // outputs per block; npts <= 224*8 = 1792
#define GTHR  1e-4f
#define NITF  14            // fast-path fixed iteration count (r <= 26)
#define NQ    534           // fast-path staged quads (max swz read idx 531)
// pool layout (floats)
#define CVP_F  2136         // cvp after staged data (2112 floats)
#define ASEG_F 4248         // int[256]
#define POOL_F 4504         // 18016 B -> 8 blocks/CU

// ---------------------------------------------------------------------------
// exact replication of np.linspace element values (float64); div-free seed
// ---------------------------------------------------------------------------
__device__ __forceinline__ double vnat(int i, double h, int N) {
    if (i == N - 1) return 10501.0;
    return __dadd_rn(__dmul_rn((double)i, h), 9999.0);
}

__device__ __forceinline__ int seg_start(int e, double h, double inv_h, int N) {
    double E = (e >= 500000) ? 10500.0
                             : __dadd_rn(__dmul_rn((double)e, 0.001), 10000.0);
    double g = __dmul_rn(E - 9999.0, inv_h);
    int i = (int)g - 2;
    if (i < 0) i = 0;
    if (i > N) i = N;
    while (i < N && vnat(i, h, N) <= E) ++i;      // exact upward fixup
    while (i > 0 && vnat(i - 1, h, N) > E) --i;   // exact downward fixup
    return i;
}

__device__ __forceinline__ float continuum(int o, const float* __restrict__ wt,
                                           float bias0) {
    double eo  = 10000.0 + (double)o * 0.001;
    double eo1 = 10000.0 + (double)(o + 1) * 0.001;
    double ci  = 0.5 * (eo + eo1);
    double cA  = 0.5 * ((10000.0 + 249999.0 * 0.001) + (10000.0 + 250000.0 * 0.001));
    double cB  = 0.5 * ((10000.0 + 250000.0 * 0.001) + (10000.0 + 250001.0 * 0.001));
    double med = 0.5 * (cA + cB);
    float x = (float)((ci - med) * (1.0 / 20500.0));
    float c = bias0;
    float p = x;
    #pragma unroll
    for (int q = 0; q < 15; ++q) {
        c = fmaf(wt[q], p, c);
        p *= x;
    }
    return c;
}

__device__ __forceinline__ int swz(int p) { return p ^ ((p >> 3) & 1); }

__device__ __forceinline__ float rlane(float v, int k) {
    return __uint_as_float(__builtin_amdgcn_readlane(__float_as_uint(v), k));
}

// ---------------------------------------------------------------------------
// Single fused kernel, 18 KB LDS pool (8 blocks/CU), stage-first prologue.
// Fast path (r<=26): VPT=8 sliding window, XOR-swizzled data LDS (ONE
// ds_read_b128 per 32 FMAs); gauss in SGPRs via one-expf-per-lane + readlane.
// Fallback (cold): global-read conv, correctness only.
// ---------------------------------------------------------------------------
__global__ __launch_bounds__(BLOCK, 8) void fused_kernel(
        const float* __restrict__ a,
        const float* __restrict__ ln_sigma,
        const float* __restrict__ weight,
        const float* __restrict__ bias,
        float* __restrict__ out,
        int N, int M) {
    __shared__ __align__(16) float pool[POOL_F];
    float* dd   = pool;                 // fast: staged data (2136 floats)
    float* sgs  = pool;                 // fallback: gauss window (<=920)
    float* cvp  = pool + CVP_F;         // padded conv results (2112)
    int*   aseg = (int*)(pool + ASEG_F);

    const int t  = threadIdx.x;
    const int b  = blockIdx.x;
    const int o1 = b * SEGS + t;
    const int s0 = b * SEGS + 1;

    const double h     = 502.0 / 3999999.0;
    const double inv_h = 3999999.0 / 502.0;

    // ---- uniform: gauss params + effective radius (cheap, fp32) ----
    const float sigma  = 0.01f + __expf(ln_sigma[0]);
    const float amp    = 0.01f / (sigma * sqrtf(6.2831853308f));
    const float inv2s2 = 0.5f / (sigma * sigma);
    int r = 450;
    float tg = amp / GTHR;
    if (tg > 1.0f) {
        float xstar = sigma * sqrtf(2.0f * __logf(tg));
        r = (int)(xstar * 100.0f) + 2;
        if (r > 450) r = 450;
    }
    const bool fast = (r <= 26);       // => nIter <= 14 for any alignment

    // ---- approx stage origin from one f64 multiply (error <= ~2) ----
    const int e0 = b * SEGS;           // = s0 - 1, always < 500000
    const double E0   = __dadd_rn(__dmul_rn((double)e0, 0.001), 10000.0);
    const double iest = __dmul_rn(E0 - 9999.0, inv_h);
    const int st0 = (((int)iest) - r - 16) & ~3;

    if (fast) {
        // ---- STAGE FIRST: swizzled quads [st0, st0 + 4*NQ) ----
        if (st0 >= 0 && st0 + (NQ << 2) <= N) {
            const float4* A4 = reinterpret_cast<const float4*>(a) + (st0 >> 2);
            float4* dw = reinterpret_cast<float4*>(dd);
            dw[swz(t)]       = A4[t];
            dw[swz(t + 256)] = A4[t + 256];
            if (t < NQ - 512) dw[swz(t + 512)] = A4[t + 512];
        } else {
            for (int j = t; j < (NQ << 2); j += BLOCK) {
                int gi = st0 + j;
                float v = (gi >= 0 && gi < N) ? a[gi] : 0.0f;
                dd[(swz(j >> 2) << 2) | (j & 3)] = v;
            }
        }
    }

    // ---- exact geometry (f64, overlaps staging latency) ----
    const int Bblk = seg_start(e0, h, inv_h, N);
    const int off2 = Bblk - 450 - st0;
    int kLo = (450 - r) - ((450 - r + off2) & 3);  // (off2+kLo) % 4 == 0
    const int kHi   = 450 + r;
    const int nIter = (kHi - kLo + 4) >> 2;
    const int i40   = (off2 + kLo) >> 2;           // in [2, 6]

    // ---- gauss -> SGPRs: one expf per lane, then readlane broadcast ----
    float G[NITF * 4];
    if (fast) {
        const int tap = kLo + (t & 63);            // in [418, 513+] ⊂ [0,900]
        const float x = (float)((tap - 450) * 0.01);
        const float gv = amp * __expf(-x * x * inv2s2);
        #pragma unroll
        for (int k = 0; k < NITF * 4; ++k) G[k] = rlane(gv, k);
    } else {
        // ---- fallback: gauss window into LDS at pool[0..] ----
        const int ntap = (nIter << 2) + 8;
        for (int j = t; j < ntap; j += BLOCK) {
            int tap = kLo + j;
            float g = 0.0f;
            if (tap >= 0 && tap <= 900) {
                float x = (float)((tap - 450) * 0.01);
                g = amp * __expf(-x * x * inv2s2);
            }
            sgs[j] = g;
        }
    }

    // ---- per-thread segment start (exact, overlaps staging) ----
    {
        int sc = s0 + t;
        if (sc > 500001) sc = 500001;
        aseg[t] = seg_start(sc - 1, h, inv_h, N);
    }
    __syncthreads();                               // barrier A

    const int A_t  = aseg[t];
    const int A_t1 = (t < 255) ? aseg[t + 1] : A_t;
    const int cnt  = (t < SEGS && o1 < M) ? (A_t1 - A_t) : 0;
    const int excl = A_t - Bblk;

    if (fast) {
        // ---- conv: VPT=8 sliding window; ONE data b128 per iteration ----
        const float4* dr = reinterpret_cast<const float4*>(dd);
        const int p0 = i40 + 2 * t;
        float4 W0 = dr[swz(p0)];
        float4 W1 = dr[swz(p0 + 1)];
        float c0=0.f,c1=0.f,c2=0.f,c3=0.f,c4=0.f,c5=0.f,c6=0.f,c7=0.f;
        #pragma unroll
        for (int m = 0; m < NITF; ++m) {
            const float4 W2 = dr[swz(p0 + m + 2)];
            const float g0 = G[4*m], g1 = G[4*m+1], g2 = G[4*m+2], g3 = G[4*m+3];
            c0 = fmaf(g0, W0.x, c0); c0 = fmaf(g1, W0.y, c0);
            c0 = fmaf(g2, W0.z, c0); c0 = fmaf(g3, W0.w, c0);
            c1 = fmaf(g0, W0.y, c1); c1 = fmaf(g1, W0.z, c1);
            c1 = fmaf(g2, W0.w, c1); c1 = fmaf(g3, W1.x, c1);
            c2 = fmaf(g0, W0.z, c2); c2 = fmaf(g1, W0.w, c2);
            c2 = fmaf(g2, W1.x, c2); c2 = fmaf(g3, W1.y, c2);
            c3 = fmaf(g0, W0.w, c3); c3 = fmaf(g1, W1.x, c3);
            c3 = fmaf(g2, W1.y, c3); c3 = fmaf(g3, W1.z, c3);
            c4 = fmaf(g0, W1.x, c4); c4 = fmaf(g1, W1.y, c4);
            c4 = fmaf(g2, W1.z, c4); c4 = fmaf(g3, W1.w, c4);
            c5 = fmaf(g0, W1.y, c5); c5 = fmaf(g1, W1.z, c5);
            c5 = fmaf(g2, W1.w, c5); c5 = fmaf(g3, W2.x, c5);
            c6 = fmaf(g0, W1.z, c6); c6 = fmaf(g1, W1.w, c6);
            c6 = fmaf(g2, W2.x, c6); c6 = fmaf(g3, W2.y, c6);
            c7 = fmaf(g0, W1.w, c7); c7 = fmaf(g1, W2.x, c7);
            c7 = fmaf(g2, W2.y, c7); c7 = fmaf(g3, W2.z, c7);
            W0 = W1; W1 = W2;
        }
        const int L = 8 * t;
        int j;
        j = L;     cvp[j + (j >> 5)] = c0;
        j = L + 1; cvp[j + (j >> 5)] = c1;
        j = L + 2; cvp[j + (j >> 5)] = c2;
        j = L + 3; cvp[j + (j >> 5)] = c3;
        j = L + 4; cvp[j + (j >> 5)] = c4;
        j = L + 5; cvp[j + (j >> 5)] = c5;
        j = L + 6; cvp[j + (j >> 5)] = c6;
        j = L + 7; cvp[j + (j >> 5)] = c7;
    } else {
        // ---- fallback conv: global reads (cold correctness path) ----
        #pragma unroll 1
        for (int u = 0; u < 8; ++u) {
            const int p = Bblk + 8 * t + u;
            float s = 0.0f;
            for (int k = kLo; k <= kHi; ++k) {
                const int gi = p + k - 450;
                const float av = (gi >= 0 && gi < N) ? a[gi] : 0.0f;
                s = fmaf(av, sgs[k - kLo], s);
            }
            const int j = 8 * t + u;
            cvp[j + (j >> 5)] = s;
        }
    }
    __syncthreads();                               // barrier B

    if (t >= SEGS || o1 >= M) return;

    float sum = 0.0f;
    for (int i = 0; i < cnt; ++i) {
        int j = excl + i;
        sum += cvp[j + (j >> 5)];
    }
    float mean = fminf(fmaxf(sum / (float)cnt, 0.0f), 1.0f);
    out[o1] = mean * continuum(o1, weight, bias[0]);
}

// ---------------------------------------------------------------------------
extern "C" void kernel_launch(void* const* d_in, const int* in_sizes, int n_in,
                              void* d_out, int out_size, void* d_ws, size_t ws_size,
                              hipStream_t stream) {
    const float* a      = (const float*)d_in[0];  // high_res_model [4M]
    const float* ln_s   = (const float*)d_in[1];  // ln_sigma [1]
    const float* weight = (const float*)d_in[2];  // [1,15]
    const float* bias   = (const float*)d_in[3];  // [1]
    float* out = (float*)d_out;

    const int N = in_sizes[0];   // 4,000,000
    const int M = out_size;      // 500,000

    const int nb = (M + SEGS - 1) / SEGS;        // 2233
    fused_kernel<<<nb, BLOCK, 0, stream>>>(a, ln_s, weight, bias, out, N, M);
}

// Round 15
// 18.130 us; speedup vs baseline: 1.2148x; 1.2148x over previous
//
#include <hip/hip_runtime.h>

#define BLOCK 256
#define SEGS  336           // outputs per block; npts <= 336*9 = 3024
#define VPT   12
#define GTHR  1e-4f
#define NITF  14            // fast-path fixed iteration count (r <= 26)
#define NQ    790           // staged quads (max read idx 786)
// pool layout (floats)
#define SGF_F  3168         // gauss replicas (544) / fallback window (<=912)
#define ASEG_F 4088         // int[337]
#define POOL_F 4432         // 17728 B -> 8 blocks/CU possible (grid-limited)

// ---------------------------------------------------------------------------
// exact replication of np.linspace element values (float64); div-free seed
// ---------------------------------------------------------------------------
__device__ __forceinline__ double vnat(int i, double h, int N) {
    if (i == N - 1) return 10501.0;
    return __dadd_rn(__dmul_rn((double)i, h), 9999.0);
}

__device__ __forceinline__ int seg_start(int e, double h, double inv_h, int N) {
    double E = (e >= 500000) ? 10500.0
                             : __dadd_rn(__dmul_rn((double)e, 0.001), 10000.0);
    double g = __dmul_rn(E - 9999.0, inv_h);
    int i = (int)g - 2;
    if (i < 0) i = 0;
    if (i > N) i = N;
    while (i < N && vnat(i, h, N) <= E) ++i;      // exact upward fixup
    while (i > 0 && vnat(i - 1, h, N) > E) --i;   // exact downward fixup
    return i;
}

__device__ __forceinline__ float continuum(int o, const float* __restrict__ wt,
                                           float bias0) {
    double eo  = 10000.0 + (double)o * 0.001;
    double eo1 = 10000.0 + (double)(o + 1) * 0.001;
    double ci  = 0.5 * (eo + eo1);
    double cA  = 0.5 * ((10000.0 + 249999.0 * 0.001) + (10000.0 + 250000.0 * 0.001));
    double cB  = 0.5 * ((10000.0 + 250000.0 * 0.001) + (10000.0 + 250001.0 * 0.001));
    double med = 0.5 * (cA + cB);
    float x = (float)((ci - med) * (1.0 / 20500.0));
    float c = bias0;
    float p = x;
    #pragma unroll
    for (int q = 0; q < 15; ++q) {
        c = fmaf(wt[q], p, c);
        p *= x;
    }
    return c;
}

// ---------------------------------------------------------------------------
// Single fused kernel, VPT=12 sliding window (2.67 LDS b128/output),
// linear staging (stride-3-quad reads are bank-floor-optimal, no swizzle),
// cvp overlaid on the dead data window (3 barriers), R13 gauss replicas.
// ---------------------------------------------------------------------------
__global__ __launch_bounds__(BLOCK, 8) void fused_kernel(
        const float* __restrict__ a,
        const float* __restrict__ ln_sigma,
        const float* __restrict__ weight,
        const float* __restrict__ bias,
        float* __restrict__ out,
        int N, int M) {
    __shared__ __align__(16) float pool[POOL_F];
    float* dd   = pool;                 // staged data [0, 3160)
    float* cvp  = pool;                 // conv results overlay [0, 3168) post-B1
    float* sgf  = pool + SGF_F;         // gauss replicas / fallback window
    int*   aseg = (int*)(pool + ASEG_F);

    const int t  = threadIdx.x;
    const int b  = blockIdx.x;
    const int s0 = b * SEGS + 1;

    const double h     = 502.0 / 3999999.0;
    const double inv_h = 3999999.0 / 502.0;

    // ---- uniform: gauss params + effective radius ----
    const float sigma  = 0.01f + __expf(ln_sigma[0]);
    const float amp    = 0.01f / (sigma * sqrtf(6.2831853308f));
    const float inv2s2 = 0.5f / (sigma * sigma);
    int r = 450;
    float tg = amp / GTHR;
    if (tg > 1.0f) {
        float xstar = sigma * sqrtf(2.0f * __logf(tg));
        r = (int)(xstar * 100.0f) + 2;
        if (r > 450) r = 450;
    }
    const bool fast = (r <= 26);       // => nIter <= 14 for any alignment

    // ---- approx stage origin from one f64 multiply (error <= ~2) ----
    const int e0 = b * SEGS;           // < 500000
    const double E0   = __dadd_rn(__dmul_rn((double)e0, 0.001), 10000.0);
    const double iest = __dmul_rn(E0 - 9999.0, inv_h);
    const int st0 = (((int)iest) - r - 16) & ~3;

    if (fast) {
        // ---- STAGE FIRST: linear quads [st0, st0 + 4*NQ) ----
        if (st0 >= 0 && st0 + (NQ << 2) <= N) {
            const float4* A4 = reinterpret_cast<const float4*>(a) + (st0 >> 2);
            float4* dw = reinterpret_cast<float4*>(dd);
            dw[t]       = A4[t];
            dw[t + 256] = A4[t + 256];
            dw[t + 512] = A4[t + 512];
            if (t < NQ - 768) dw[t + 768] = A4[t + 768];
        } else {
            for (int j = t; j < (NQ << 2); j += BLOCK) {
                int gi = st0 + j;
                dd[j] = (gi >= 0 && gi < N) ? a[gi] : 0.0f;
            }
        }
    }

    // ---- exact geometry (f64, overlaps staging latency) ----
    const int Bblk = seg_start(e0, h, inv_h, N);
    const int off2 = Bblk - 450 - st0;
    int kLo = (450 - r) - ((450 - r + off2) & 3);  // (off2+kLo) % 4 == 0
    const int kHi   = 450 + r;
    const int nIter = (kHi - kLo + 4) >> 2;
    const int i40   = (off2 + kLo) >> 2;           // in [2, 6]

    if (fast) {
        // ---- 8 bank-staggered gauss replicas: copy k at float 68k ----
        for (int j = t; j < 512; j += BLOCK) {     // 2 iterations
            const int k = j >> 6, i = j & 63;
            const int tap = kLo + i;               // ⊂ [418, 545] ⊂ [0,900]
            float x = (float)((tap - 450) * 0.01);
            sgf[68 * k + i] = amp * __expf(-x * x * inv2s2);
        }
    } else {
        // ---- fallback: gauss window at sgf[0..] ----
        const int ntap = (nIter << 2) + 8;
        for (int j = t; j < ntap; j += BLOCK) {
            int tap = kLo + j;
            float g = 0.0f;
            if (tap >= 0 && tap <= 900) {
                float x = (float)((tap - 450) * 0.01);
                g = amp * __expf(-x * x * inv2s2);
            }
            sgf[j] = g;
        }
    }

    // ---- per-thread segment starts: 337 entries over 256 threads ----
    {
        int sc = s0 + t;
        if (sc > 500001) sc = 500001;
        aseg[t] = seg_start(sc - 1, h, inv_h, N);
        if (t <= SEGS - 256) {                     // t in [0, 80]
            int sc2 = s0 + 256 + t;
            if (sc2 > 500001) sc2 = 500001;
            aseg[256 + t] = seg_start(sc2 - 1, h, inv_h, N);
        }
    }
    __syncthreads();                               // barrier A

    float c0=0.f,c1=0.f,c2=0.f,c3=0.f,c4=0.f,c5=0.f;
    float c6=0.f,c7=0.f,c8=0.f,c9=0.f,c10=0.f,c11=0.f;

    if (fast) {
        // ---- conv: VPT=12 sliding window; 1 data + 1 gauss b128 / iter ----
        const float4* dr = reinterpret_cast<const float4*>(dd);
        const float4* gr = reinterpret_cast<const float4*>(sgf) + 17 * (t & 7);
        const int p0 = i40 + 3 * t;                // max 6+765 = 771
        float4 W0 = dr[p0], W1 = dr[p0 + 1], W2 = dr[p0 + 2];
        #pragma unroll
        for (int m = 0; m < NITF; ++m) {
            const float4 W3 = dr[p0 + m + 3];      // max 771+16 = 787 < NQ
            const float4 g  = gr[m];
            c0  = fmaf(g.x, W0.x, c0);  c0  = fmaf(g.y, W0.y, c0);
            c0  = fmaf(g.z, W0.z, c0);  c0  = fmaf(g.w, W0.w, c0);
            c1  = fmaf(g.x, W0.y, c1);  c1  = fmaf(g.y, W0.z, c1);
            c1  = fmaf(g.z, W0.w, c1);  c1  = fmaf(g.w, W1.x, c1);
            c2  = fmaf(g.x, W0.z, c2);  c2  = fmaf(g.y, W0.w, c2);
            c2  = fmaf(g.z, W1.x, c2);  c2  = fmaf(g.w, W1.y, c2);
            c3  = fmaf(g.x, W0.w, c3);  c3  = fmaf(g.y, W1.x, c3);
            c3  = fmaf(g.z, W1.y, c3);  c3  = fmaf(g.w, W1.z, c3);
            c4  = fmaf(g.x, W1.x, c4);  c4  = fmaf(g.y, W1.y, c4);
            c4  = fmaf(g.z, W1.z, c4);  c4  = fmaf(g.w, W1.w, c4);
            c5  = fmaf(g.x, W1.y, c5);  c5  = fmaf(g.y, W1.z, c5);
            c5  = fmaf(g.z, W1.w, c5);  c5  = fmaf(g.w, W2.x, c5);
            c6  = fmaf(g.x, W1.z, c6);  c6  = fmaf(g.y, W1.w, c6);
            c6  = fmaf(g.z, W2.x, c6);  c6  = fmaf(g.w, W2.y, c6);
            c7  = fmaf(g.x, W1.w, c7);  c7  = fmaf(g.y, W2.x, c7);
            c7  = fmaf(g.z, W2.y, c7);  c7  = fmaf(g.w, W2.z, c7);
            c8  = fmaf(g.x, W2.x, c8);  c8  = fmaf(g.y, W2.y, c8);
            c8  = fmaf(g.z, W2.z, c8);  c8  = fmaf(g.w, W2.w, c8);
            c9  = fmaf(g.x, W2.y, c9);  c9  = fmaf(g.y, W2.z, c9);
            c9  = fmaf(g.z, W2.w, c9);  c9  = fmaf(g.w, W3.x, c9);
            c10 = fmaf(g.x, W2.z, c10); c10 = fmaf(g.y, W2.w, c10);
            c10 = fmaf(g.z, W3.x, c10); c10 = fmaf(g.w, W3.y, c10);
            c11 = fmaf(g.x, W2.w, c11); c11 = fmaf(g.y, W3.x, c11);
            c11 = fmaf(g.z, W3.y, c11); c11 = fmaf(g.w, W3.z, c11);
            W0 = W1; W1 = W2; W2 = W3;
        }
    } else {
        // ---- fallback conv: global reads (cold correctness path) ----
        float acc[VPT];
        #pragma unroll 1
        for (int u = 0; u < VPT; ++u) {
            const int p = Bblk + VPT * t + u;
            float s = 0.0f;
            for (int k = kLo; k <= kHi; ++k) {
                const int gi = p + k - 450;
                const float av = (gi >= 0 && gi < N) ? a[gi] : 0.0f;
                s = fmaf(av, sgf[k - kLo], s);
            }
            acc[u] = s;
        }
        c0 = acc[0]; c1 = acc[1]; c2 = acc[2]; c3 = acc[3];
        c4 = acc[4]; c5 = acc[5]; c6 = acc[6]; c7 = acc[7];
        c8 = acc[8]; c9 = acc[9]; c10 = acc[10]; c11 = acc[11];
    }
    __syncthreads();                               // barrier B1: dd reads done

    // ---- cvp overlay writes (padded, conflict-spread) ----
    {
        const int L = VPT * t;
        int j;
        j = L;      cvp[j + (j >> 5)] = c0;
        j = L + 1;  cvp[j + (j >> 5)] = c1;
        j = L + 2;  cvp[j + (j >> 5)] = c2;
        j = L + 3;  cvp[j + (j >> 5)] = c3;
        j = L + 4;  cvp[j + (j >> 5)] = c4;
        j = L + 5;  cvp[j + (j >> 5)] = c5;
        j = L + 6;  cvp[j + (j >> 5)] = c6;
        j = L + 7;  cvp[j + (j >> 5)] = c7;
        j = L + 8;  cvp[j + (j >> 5)] = c8;
        j = L + 9;  cvp[j + (j >> 5)] = c9;
        j = L + 10; cvp[j + (j >> 5)] = c10;
        j = L + 11; cvp[j + (j >> 5)] = c11;
    }
    __syncthreads();                               // barrier B2: cvp visible

    // ---- segment means: thread t does segment t (+ segment 256+t if t<80) ----
    const float b0 = bias[0];
    {
        const int o1 = b * SEGS + t;
        if (o1 < M) {
            const int A0 = aseg[t], A1 = aseg[t + 1];
            const int cnt = A1 - A0, excl = A0 - Bblk;
            float sum = 0.0f;
            for (int i = 0; i < cnt; ++i) {
                int j = excl + i;
                sum += cvp[j + (j >> 5)];
            }
            float mean = fminf(fmaxf(sum / (float)cnt, 0.0f), 1.0f);
            out[o1] = mean * continuum(o1, weight, b0);
        }
    }
    if (t < SEGS - 256) {                          // t in [0, 80)
        const int o2 = b * SEGS + 256 + t;
        if (o2 < M) {
            const int A0 = aseg[256 + t], A1 = aseg[257 + t];
            const int cnt = A1 - A0, excl = A0 - Bblk;
            float sum = 0.0f;
            for (int i = 0; i < cnt; ++i) {
                int j = excl + i;
                sum += cvp[j + (j >> 5)];
            }
            float mean = fminf(fmaxf(sum / (float)cnt, 0.0f), 1.0f);
            out[o2] = mean * continuum(o2, weight, b0);
        }
    }
}

// ---------------------------------------------------------------------------
extern "C" void kernel_launch(void* const* d_in, const int* in_sizes, int n_in,
                              void* d_out, int out_size, void* d_ws, size_t ws_size,
                              hipStream_t stream) {
    const float* a      = (const float*)d_in[0];  // high_res_model [4M]
    const float* ln_s   = (const float*)d_in[1];  // ln_sigma [1]
    const float* weight = (const float*)d_in[2];  // [1,15]
    const float* bias   = (const float*)d_in[3];  // [1]
    float* out = (float*)d_out;

    const int N = in_sizes[0];   // 4,000,000
    const int M = out_size;      // 500,000

    const int nb = (M + SEGS - 1) / SEGS;        // 1489
    fused_kernel<<<nb, BLOCK, 0, stream>>>(a, ln_s, weight, bias, out, N, M);
}

// Round 16
// 17.899 us; speedup vs baseline: 1.2305x; 1.0129x over previous
//
#include <hip/hip_runtime.h>

#define BLOCK 256
#define SEGS  336           // outputs per block; npts <= 336*9 = 3024
#define VPT   12
#define GTHR  5e-4f
#define NITF  13            // fast-path fixed iteration count (r <= 24)
#define NQ    788           // staged quads (max read idx 785)
// pool layout (floats)
#define SGF_F  3168         // gauss replicas (544) / fallback window (<=912)
#define ASEG_F 4088         // int[337]
#define POOL_F 4432         // 17728 B

// ---------------------------------------------------------------------------
// exact replication of np.linspace element values (float64); div-free seed
// ---------------------------------------------------------------------------
__device__ __forceinline__ double vnat(int i, double h, int N) {
    if (i == N - 1) return 10501.0;
    return __dadd_rn(__dmul_rn((double)i, h), 9999.0);
}

__device__ __forceinline__ int seg_start(int e, double h, double inv_h, int N) {
    double E = (e >= 500000) ? 10500.0
                             : __dadd_rn(__dmul_rn((double)e, 0.001), 10000.0);
    double g = __dmul_rn(E - 9999.0, inv_h);
    int i = (int)g - 2;
    if (i < 0) i = 0;
    if (i > N) i = N;
    while (i < N && vnat(i, h, N) <= E) ++i;      // exact upward fixup
    while (i > 0 && vnat(i - 1, h, N) > E) --i;   // exact downward fixup
    return i;
}

__device__ __forceinline__ float continuum(int o, const float* __restrict__ wt,
                                           float bias0) {
    double eo  = 10000.0 + (double)o * 0.001;
    double eo1 = 10000.0 + (double)(o + 1) * 0.001;
    double ci  = 0.5 * (eo + eo1);
    double cA  = 0.5 * ((10000.0 + 249999.0 * 0.001) + (10000.0 + 250000.0 * 0.001));
    double cB  = 0.5 * ((10000.0 + 250000.0 * 0.001) + (10000.0 + 250001.0 * 0.001));
    double med = 0.5 * (cA + cB);
    float x = (float)((ci - med) * (1.0 / 20500.0));
    float c = bias0;
    float p = x;
    #pragma unroll
    for (int q = 0; q < 15; ++q) {
        c = fmaf(wt[q], p, c);
        p *= x;
    }
    return c;
}

// async global -> LDS, 16 B per lane; lptr is the wave-uniform base
__device__ __forceinline__ void gload16(const float* g, float* l) {
    __builtin_amdgcn_global_load_lds(
        (const __attribute__((address_space(1))) void*)g,
        (__attribute__((address_space(3))) void*)l, 16, 0, 0);
}

// ---------------------------------------------------------------------------
// Single fused kernel: VPT=12 sliding window, linear staging via
// global_load_lds (width 16, no VGPR round-trip), bank-staggered gauss
// replicas, cvp overlaid on the dead data window.
// ---------------------------------------------------------------------------
__global__ __launch_bounds__(BLOCK, 8) void fused_kernel(
        const float* __restrict__ a,
        const float* __restrict__ ln_sigma,
        const float* __restrict__ weight,
        const float* __restrict__ bias,
        float* __restrict__ out,
        int N, int M) {
    __shared__ __align__(16) float pool[POOL_F];
    float* dd   = pool;                 // staged data [0, 3152)
    float* cvp  = pool;                 // conv overlay (post barrier B1)
    float* sgf  = pool + SGF_F;         // gauss replicas / fallback window
    int*   aseg = (int*)(pool + ASEG_F);

    const int t  = threadIdx.x;
    const int b  = blockIdx.x;
    const int s0 = b * SEGS + 1;

    const double h     = 502.0 / 3999999.0;
    const double inv_h = 3999999.0 / 502.0;

    // ---- uniform: gauss params + effective radius ----
    const float sigma  = 0.01f + __expf(ln_sigma[0]);
    const float amp    = 0.01f / (sigma * sqrtf(6.2831853308f));
    const float inv2s2 = 0.5f / (sigma * sigma);
    int r = 450;
    float tg = amp / GTHR;
    if (tg > 1.0f) {
        float xstar = sigma * sqrtf(2.0f * __logf(tg));
        r = (int)(xstar * 100.0f) + 2;
        if (r > 450) r = 450;
    }
    const bool fast = (r <= 24);       // => nIter <= 13 for any alignment

    // ---- approx stage origin from one f64 multiply (error <= ~2) ----
    const int e0 = b * SEGS;           // < 500000
    const double E0   = __dadd_rn(__dmul_rn((double)e0, 0.001), 10000.0);
    const double iest = __dmul_rn(E0 - 9999.0, inv_h);
    const int st0 = (((int)iest) - r - 16) & ~3;

    if (fast) {
        // ---- STAGE FIRST: async DMA, linear quads [st0, st0 + 4*NQ) ----
        if (st0 >= 0 && st0 + (NQ << 2) <= N) {
            const float* gsrc = a + st0 + 4 * t;
            float* lb = dd + 256 * (t >> 6);       // wave-uniform base
            gload16(gsrc,                lb);
            gload16(gsrc + 1024,         lb + 1024);
            gload16(gsrc + 2048,         lb + 2048);
            if (t < NQ - 768) gload16(gsrc + 3072, lb + 3072);
        } else {
            for (int j = t; j < (NQ << 2); j += BLOCK) {
                int gi = st0 + j;
                dd[j] = (gi >= 0 && gi < N) ? a[gi] : 0.0f;
            }
        }
    }

    // ---- exact geometry (f64, overlaps staging latency) ----
    const int Bblk = seg_start(e0, h, inv_h, N);
    const int off2 = Bblk - 450 - st0;
    int kLo = (450 - r) - ((450 - r + off2) & 3);  // (off2+kLo) % 4 == 0
    const int kHi   = 450 + r;
    const int nIter = (kHi - kLo + 4) >> 2;
    const int i40   = (off2 + kLo) >> 2;           // in [2, 5]

    if (fast) {
        // ---- 8 bank-staggered gauss replicas: copy k at float 68k ----
        for (int j = t; j < 512; j += BLOCK) {     // 2 iterations
            const int k = j >> 6, i = j & 63;
            const int tap = kLo + i;               // ⊂ [420, 491] ⊂ [0,900]
            float x = (float)((tap - 450) * 0.01);
            sgf[68 * k + i] = amp * __expf(-x * x * inv2s2);
        }
    } else {
        // ---- fallback: gauss window at sgf[0..] ----
        const int ntap = (nIter << 2) + 8;
        for (int j = t; j < ntap; j += BLOCK) {
            int tap = kLo + j;
            float g = 0.0f;
            if (tap >= 0 && tap <= 900) {
                float x = (float)((tap - 450) * 0.01);
                g = amp * __expf(-x * x * inv2s2);
            }
            sgf[j] = g;
        }
    }

    // ---- per-thread segment starts: 337 entries over 256 threads ----
    {
        int sc = s0 + t;
        if (sc > 500001) sc = 500001;
        aseg[t] = seg_start(sc - 1, h, inv_h, N);
        if (t <= SEGS - 256) {                     // t in [0, 80]
            int sc2 = s0 + 256 + t;
            if (sc2 > 500001) sc2 = 500001;
            aseg[256 + t] = seg_start(sc2 - 1, h, inv_h, N);
        }
    }
    __syncthreads();                               // barrier A (drains DMA)

    float c0=0.f,c1=0.f,c2=0.f,c3=0.f,c4=0.f,c5=0.f;
    float c6=0.f,c7=0.f,c8=0.f,c9=0.f,c10=0.f,c11=0.f;

    if (fast) {
        // ---- conv: VPT=12 sliding window; 1 data + 1 gauss b128 / iter ----
        const float4* dr = reinterpret_cast<const float4*>(dd);
        const float4* gr = reinterpret_cast<const float4*>(sgf) + 17 * (t & 7);
        const int p0 = i40 + 3 * t;                // max 5+765 = 770
        float4 W0 = dr[p0], W1 = dr[p0 + 1], W2 = dr[p0 + 2];
        #pragma unroll
        for (int m = 0; m < NITF; ++m) {
            const float4 W3 = dr[p0 + m + 3];      // max 770+15 = 785 < NQ
            const float4 g  = gr[m];
            c0  = fmaf(g.x, W0.x, c0);  c0  = fmaf(g.y, W0.y, c0);
            c0  = fmaf(g.z, W0.z, c0);  c0  = fmaf(g.w, W0.w, c0);
            c1  = fmaf(g.x, W0.y, c1);  c1  = fmaf(g.y, W0.z, c1);
            c1  = fmaf(g.z, W0.w, c1);  c1  = fmaf(g.w, W1.x, c1);
            c2  = fmaf(g.x, W0.z, c2);  c2  = fmaf(g.y, W0.w, c2);
            c2  = fmaf(g.z, W1.x, c2);  c2  = fmaf(g.w, W1.y, c2);
            c3  = fmaf(g.x, W0.w, c3);  c3  = fmaf(g.y, W1.x, c3);
            c3  = fmaf(g.z, W1.y, c3);  c3  = fmaf(g.w, W1.z, c3);
            c4  = fmaf(g.x, W1.x, c4);  c4  = fmaf(g.y, W1.y, c4);
            c4  = fmaf(g.z, W1.z, c4);  c4  = fmaf(g.w, W1.w, c4);
            c5  = fmaf(g.x, W1.y, c5);  c5  = fmaf(g.y, W1.z, c5);
            c5  = fmaf(g.z, W1.w, c5);  c5  = fmaf(g.w, W2.x, c5);
            c6  = fmaf(g.x, W1.z, c6);  c6  = fmaf(g.y, W1.w, c6);
            c6  = fmaf(g.z, W2.x, c6);  c6  = fmaf(g.w, W2.y, c6);
            c7  = fmaf(g.x, W1.w, c7);  c7  = fmaf(g.y, W2.x, c7);
            c7  = fmaf(g.z, W2.y, c7);  c7  = fmaf(g.w, W2.z, c7);
            c8  = fmaf(g.x, W2.x, c8);  c8  = fmaf(g.y, W2.y, c8);
            c8  = fmaf(g.z, W2.z, c8);  c8  = fmaf(g.w, W2.w, c8);
            c9  = fmaf(g.x, W2.y, c9);  c9  = fmaf(g.y, W2.z, c9);
            c9  = fmaf(g.z, W2.w, c9);  c9  = fmaf(g.w, W3.x, c9);
            c10 = fmaf(g.x, W2.z, c10); c10 = fmaf(g.y, W2.w, c10);
            c10 = fmaf(g.z, W3.x, c10); c10 = fmaf(g.w, W3.y, c10);
            c11 = fmaf(g.x, W2.w, c11); c11 = fmaf(g.y, W3.x, c11);
            c11 = fmaf(g.z, W3.y, c11); c11 = fmaf(g.w, W3.z, c11);
            W0 = W1; W1 = W2; W2 = W3;
        }
    } else {
        // ---- fallback conv: global reads (cold correctness path) ----
        float acc[VPT];
        #pragma unroll 1
        for (int u = 0; u < VPT; ++u) {
            const int p = Bblk + VPT * t + u;
            float s = 0.0f;
            for (int k = kLo; k <= kHi; ++k) {
                const int gi = p + k - 450;
                const float av = (gi >= 0 && gi < N) ? a[gi] : 0.0f;
                s = fmaf(av, sgf[k - kLo], s);
            }
            acc[u] = s;
        }
        c0 = acc[0]; c1 = acc[1]; c2 = acc[2];  c3 = acc[3];
        c4 = acc[4]; c5 = acc[5]; c6 = acc[6];  c7 = acc[7];
        c8 = acc[8]; c9 = acc[9]; c10 = acc[10]; c11 = acc[11];
    }
    __syncthreads();                               // barrier B1: dd reads done

    // ---- cvp overlay writes (padded, conflict-spread) ----
    {
        const int L = VPT * t;
        int j;
        j = L;      cvp[j + (j >> 5)] = c0;
        j = L + 1;  cvp[j + (j >> 5)] = c1;
        j = L + 2;  cvp[j + (j >> 5)] = c2;
        j = L + 3;  cvp[j + (j >> 5)] = c3;
        j = L + 4;  cvp[j + (j >> 5)] = c4;
        j = L + 5;  cvp[j + (j >> 5)] = c5;
        j = L + 6;  cvp[j + (j >> 5)] = c6;
        j = L + 7;  cvp[j + (j >> 5)] = c7;
        j = L + 8;  cvp[j + (j >> 5)] = c8;
        j = L + 9;  cvp[j + (j >> 5)] = c9;
        j = L + 10; cvp[j + (j >> 5)] = c10;
        j = L + 11; cvp[j + (j >> 5)] = c11;
    }
    __syncthreads();                               // barrier B2: cvp visible

    // ---- segment means: thread t -> segment t (+ 256+t if t < 80) ----
    const float b0 = bias[0];
    {
        const int o1 = b * SEGS + t;
        if (o1 < M) {
            const int A0 = aseg[t], A1 = aseg[t + 1];
            const int cnt = A1 - A0, excl = A0 - Bblk;
            float sum = 0.0f;
            for (int i = 0; i < cnt; ++i) {
                int j = excl + i;
                sum += cvp[j + (j >> 5)];
            }
            float mean = fminf(fmaxf(sum / (float)cnt, 0.0f), 1.0f);
            out[o1] = mean * continuum(o1, weight, b0);
        }
    }
    if (t < SEGS - 256) {                          // t in [0, 80)
        const int o2 = b * SEGS + 256 + t;
        if (o2 < M) {
            const int A0 = aseg[256 + t], A1 = aseg[257 + t];
            const int cnt = A1 - A0, excl = A0 - Bblk;
            float sum = 0.0f;
            for (int i = 0; i < cnt; ++i) {
                int j = excl + i;
                sum += cvp[j + (j >> 5)];
            }
            float mean = fminf(fmaxf(sum / (float)cnt, 0.0f), 1.0f);
            out[o2] = mean * continuum(o2, weight, b0);
        }
    }
}

// ---------------------------------------------------------------------------
extern "C" void kernel_launch(void* const* d_in, const int* in_sizes, int n_in,
                              void* d_out, int out_size, void* d_ws, size_t ws_size,
                              hipStream_t stream) {
    const float* a      = (const float*)d_in[0];  // high_res_model [4M]
    const float* ln_s   = (const float*)d_in[1];  // ln_sigma [1]
    const float* weight = (const float*)d_in[2];  // [1,15]
    const float* bias   = (const float*)d_in[3];  // [1]
    float* out = (float*)d_out;

    const int N = in_sizes[0];   // 4,000,000
    const int M = out_size;      // 500,000

    const int nb = (M + SEGS - 1) / SEGS;        // 1489
    fused_kernel<<<nb, BLOCK, 0, stream>>>(a, ln_s, weight, bias, out, N, M);
}